// Round 1
// baseline (17384.015 us; speedup 1.0000x reference)
//
#include <hip/hip_runtime.h>

// ---------------------------------------------------------------------------
// CLIP text transformer forward, MI355X/gfx950.
// Shapes: N=64, L=77, D=768, V=8, M=8, H=12 heads (hd=64), 12 layers.
// Rows = M*N*L = 39424 = 308*128 (exact 128-row tiles, no edge handling).
// Strategy round 1: fp32 residual h, bf16 activations + bf16 MFMA GEMMs
// (weights converted fp32->bf16 during LDS staging; each weight read once),
// fused per-(batch,head) attention with fp32 softmax.
// ---------------------------------------------------------------------------

typedef short short8 __attribute__((ext_vector_type(8)));
typedef float floatx4 __attribute__((ext_vector_type(4)));
typedef unsigned int uint4v __attribute__((ext_vector_type(4)));
typedef unsigned short ushort4v __attribute__((ext_vector_type(4)));

#define SOV_TOK 49408
#define EOT_TOK 49407
#define ROWS 39424      // 512*77
#define DMODEL 768

__device__ __forceinline__ unsigned short f2bf(float f) {
  union { float f; unsigned int u; } v; v.f = f;
  return (unsigned short)((v.u + 0x7fffu + ((v.u >> 16) & 1u)) >> 16);
}

__device__ __forceinline__ float blockReduceSum256(float v, float* red) {
  __syncthreads();                    // protect red reuse across calls
  #pragma unroll
  for (int off = 32; off; off >>= 1) v += __shfl_down(v, off, 64);
  int wave = threadIdx.x >> 6, lane = threadIdx.x & 63;
  if (lane == 0) red[wave] = v;
  __syncthreads();
  return red[0] + red[1] + red[2] + red[3];
}

// ---------------- index scan: first SOV / first EOT per sequence ----------
__global__ void idx_kernel(const int* text, int* posy, int* eot) {
  int n = threadIdx.x;  // 64 threads
  int py = 0, et = 0; bool fp = false, fe = false;
  for (int j = 0; j < 77; j++) {
    int v = text[n * 77 + j];
    if (!fp && v == SOV_TOK) { py = j; fp = true; }
    if (!fe && v == EOT_TOK) { et = j; fe = true; }
  }
  posy[n] = py; eot[n] = et;
}

// ---------------- transpose text_proj (D,E) -> (E,D) fp32 -----------------
__global__ void transT_kernel(const float* tp, float* wt) {
  int id = blockIdx.x * 256 + threadIdx.x;   // 768*768 total
  int d = id / 768, e = id % 768;
  wt[(size_t)e * 768 + d] = tp[id];
}

// ---------------- build h = splice(tok_emb, visual) + pos_emb -------------
__global__ void embed_kernel(const int* text, const float* vis,
                             const float* tok_emb, const float* pos_emb,
                             const int* posy, float* h) {
  int bp = blockIdx.x;              // 0..39423 = b*77+p
  int b = bp / 77, p = bp % 77;
  int mm = b >> 6, n = b & 63;
  int py = posy[n];
  int t = threadIdx.x;              // 192 threads * float4 = 768
  const float* srcp;
  if (p >= py && p < py + 8) {
    srcp = vis + ((size_t)mm * 8 + (p - py)) * 768;
  } else {
    int src = (p < py) ? p : p - 7;
    src = src < 0 ? 0 : (src > 76 ? 76 : src);
    int tok = text[n * 77 + src];
    srcp = tok_emb + (size_t)tok * 768;
  }
  float4 v = *(const float4*)(srcp + t * 4);
  float4 pe = *(const float4*)(pos_emb + (size_t)p * 768 + t * 4);
  v.x += pe.x; v.y += pe.y; v.z += pe.z; v.w += pe.w;
  *(float4*)(h + (size_t)bp * 768 + t * 4) = v;
}

// ---------------- row LayerNorm fp32 -> bf16 ------------------------------
__device__ __forceinline__ void ln_row(const float* xr, const float* w,
                                       const float* b, unsigned short* yr,
                                       float* red) {
  int t = threadIdx.x;  // 256
  float v0 = xr[t], v1 = xr[t + 256], v2 = xr[t + 512];
  float s = blockReduceSum256(v0 + v1 + v2, red);
  float mu = s * (1.f / 768.f);
  float d0 = v0 - mu, d1 = v1 - mu, d2 = v2 - mu;
  float q = blockReduceSum256(d0 * d0 + d1 * d1 + d2 * d2, red);
  float rstd = rsqrtf(q * (1.f / 768.f) + 1e-5f);
  yr[t]       = f2bf(d0 * rstd * w[t]       + b[t]);
  yr[t + 256] = f2bf(d1 * rstd * w[t + 256] + b[t + 256]);
  yr[t + 512] = f2bf(d2 * rstd * w[t + 512] + b[t + 512]);
}

__global__ void ln_kernel(const float* x, const float* w, const float* b,
                          unsigned short* y) {
  __shared__ float red[4];
  size_t r = blockIdx.x;
  ln_row(x + r * 768, w, b, y + r * 768, red);
}

// gather the (eot+V-1) token per (m,n) and apply final LN
__global__ void gather_ln_kernel(const float* h, const int* eot,
                                 const float* w, const float* b,
                                 unsigned short* y) {
  __shared__ float red[4];
  int r = blockIdx.x;               // 0..511 = m*64+n
  int n = r & 63;
  size_t row = (size_t)r * 77 + (eot[n] + 7);
  ln_row(h + row * 768, w, b, y + (size_t)r * 768, red);
}

// ---------------- GEMM: C[rows,cols] = A_bf16[rows,K] @ W_f32[cols,K]^T ---
// MODE 0: +bias -> bf16    MODE 1: gelu(+bias) -> bf16
// MODE 2: h += (+bias), fp32 in/out    MODE 3: (+bias?) -> fp32
template <int MODE>
__global__ __launch_bounds__(256, 2)
void gemm_kernel(const unsigned short* A, const float* W, const float* bias,
                 void* outp, const float* resid, int K, int cols) {
  __shared__ __align__(16) unsigned short As[128 * 32];
  __shared__ __align__(16) unsigned short Ws[128 * 32];
  int row0 = blockIdx.x * 128;
  int col0 = blockIdx.y * 128;
  int t = threadIdx.x;
  int wave = t >> 6, lane = t & 63;
  int wr = (wave & 1) * 64;   // wave's 64-row strip
  int wc = (wave >> 1) * 64;  // wave's 64-col strip
  int m = lane & 15, quad = lane >> 4;
  int arow0 = t >> 2, akc = (t & 3) * 8;   // A staging: 16B chunks

  floatx4 acc[4][4] = {};

  for (int kb = 0; kb < K; kb += 32) {
    const unsigned short* Ab = A + (size_t)row0 * K + kb;
    uint4v a0 = *(const uint4v*)(Ab + (size_t)arow0 * K + akc);
    uint4v a1 = *(const uint4v*)(Ab + (size_t)(arow0 + 64) * K + akc);
    const float* Wb = W + (size_t)col0 * K + kb;
    float4 wv[4];
    #pragma unroll
    for (int i = 0; i < 4; i++) {
      int c = t + 256 * i; int col = c >> 3; int kq = (c & 7) * 4;
      wv[i] = *(const float4*)(Wb + (size_t)col * K + kq);
    }
    __syncthreads();   // previous iter's MFMA reads done
    *(uint4v*)(As + arow0 * 32 + akc) = a0;
    *(uint4v*)(As + (arow0 + 64) * 32 + akc) = a1;
    #pragma unroll
    for (int i = 0; i < 4; i++) {
      int c = t + 256 * i; int col = c >> 3; int kq = (c & 7) * 4;
      ushort4v wb;
      wb.x = f2bf(wv[i].x); wb.y = f2bf(wv[i].y);
      wb.z = f2bf(wv[i].z); wb.w = f2bf(wv[i].w);
      *(ushort4v*)(Ws + col * 32 + kq) = wb;
    }
    __syncthreads();
    short8 af[4], bfm[4];
    #pragma unroll
    for (int i = 0; i < 4; i++)
      af[i] = *(const short8*)(As + (wr + i * 16 + m) * 32 + quad * 8);
    #pragma unroll
    for (int j = 0; j < 4; j++)
      bfm[j] = *(const short8*)(Ws + (wc + j * 16 + m) * 32 + quad * 8);
    #pragma unroll
    for (int i = 0; i < 4; i++)
      #pragma unroll
      for (int j = 0; j < 4; j++)
        acc[i][j] = __builtin_amdgcn_mfma_f32_16x16x32_bf16(af[i], bfm[j],
                                                            acc[i][j], 0, 0, 0);
  }

  // epilogue: C/D layout col = lane&15, row = quad*4+reg
  #pragma unroll
  for (int i = 0; i < 4; i++) {
    #pragma unroll
    for (int j = 0; j < 4; j++) {
      int c = col0 + wc + j * 16 + m;
      float bi = bias ? bias[c] : 0.f;
      int rbase = row0 + wr + i * 16 + quad * 4;
      #pragma unroll
      for (int reg = 0; reg < 4; reg++) {
        size_t idx = (size_t)(rbase + reg) * cols + c;
        float v = acc[i][j][reg] + bi;
        if (MODE == 0) {
          ((unsigned short*)outp)[idx] = f2bf(v);
        } else if (MODE == 1) {
          float g = v / (1.f + __expf(-1.702f * v));
          ((unsigned short*)outp)[idx] = f2bf(g);
        } else if (MODE == 2) {
          float* op = (float*)outp;
          op[idx] = resid[idx] + v;
        } else {
          ((float*)outp)[idx] = v;
        }
      }
    }
  }
}

// ---------------- fused attention per (batch, head) -----------------------
// QK^T via MFMA (lower-triangular tiles only), fp32 softmax, P@V via MFMA.
__global__ __launch_bounds__(256)
void attn_kernel(const unsigned short* qkv, unsigned short* o) {
  __shared__ __align__(16) union U {
    struct { unsigned short Qs[80 * 64]; unsigned short Ks[80 * 64]; } qk;
    unsigned short Ps[80 * 96];
  } u;
  __shared__ __align__(16) unsigned short Vt[64 * 96];
  __shared__ float S[80 * 81];     // stride 81: bank-conflict-free rows

  int b = blockIdx.x, hh = blockIdx.y;
  int t = threadIdx.x, wave = t >> 6, lane = t & 63;
  int m = lane & 15, quad = lane >> 4;
  const unsigned short* base = qkv + (size_t)b * 77 * 2304 + hh * 64;

  // stage Q,K rows (pad rows 77..79 with zeros)
  for (int c = t; c < 640; c += 256) {
    int l = c >> 3, kc = (c & 7) * 8;
    uint4v q = {0, 0, 0, 0}, k = {0, 0, 0, 0};
    if (l < 77) {
      q = *(const uint4v*)(base + (size_t)l * 2304 + kc);
      k = *(const uint4v*)(base + (size_t)l * 2304 + 768 + kc);
    }
    *(uint4v*)(u.qk.Qs + l * 64 + kc) = q;
    *(uint4v*)(u.qk.Ks + l * 64 + kc) = k;
  }
  // stage V transposed: Vt[d][l], l padded to 96
  for (int c = t; c < 768; c += 256) {
    int l = c >> 3, d0 = (c & 7) * 8;
    union { uint4v v; unsigned short s[8]; } vv;
    vv.v = (uint4v){0, 0, 0, 0};
    if (l < 77) vv.v = *(const uint4v*)(base + (size_t)l * 2304 + 1536 + d0);
    #pragma unroll
    for (int j = 0; j < 8; j++) Vt[(d0 + j) * 96 + l] = vv.s[j];
  }
  __syncthreads();

  // S = Q K^T : lower-triangular 16x16 tiles (15 of 25)
  for (int idx = wave; idx < 15; idx += 4) {
    int ti = 0, a2 = 0;
    while (a2 + ti + 1 <= idx) { a2 += ti + 1; ti++; }
    int tj = idx - a2;
    floatx4 sa = {};
    #pragma unroll
    for (int k0 = 0; k0 < 64; k0 += 32) {
      short8 aq = *(const short8*)(u.qk.Qs + (ti * 16 + m) * 64 + k0 + quad * 8);
      short8 bk = *(const short8*)(u.qk.Ks + (tj * 16 + m) * 64 + k0 + quad * 8);
      sa = __builtin_amdgcn_mfma_f32_16x16x32_bf16(aq, bk, sa, 0, 0, 0);
    }
    #pragma unroll
    for (int r = 0; r < 4; r++)
      S[(ti * 16 + quad * 4 + r) * 81 + tj * 16 + m] = sa[r];
  }
  __syncthreads();

  // causal softmax row-per-thread (scale 1/8), write P bf16 (96-padded)
  if (t < 80) {
    int r = t;
    if (r < 77) {
      float mx = -1e30f;
      for (int j = 0; j <= r; j++) mx = fmaxf(mx, S[r * 81 + j]);
      float sum = 0.f;
      for (int j = 0; j <= r; j++) {
        float e = __expf((S[r * 81 + j] - mx) * 0.125f);
        S[r * 81 + j] = e; sum += e;
      }
      float inv = 1.f / sum;
      for (int j = 0; j < 96; j++)
        u.Ps[r * 96 + j] = (j <= r) ? f2bf(S[r * 81 + j] * inv) : (unsigned short)0;
    } else {
      for (int j = 0; j < 96; j++) u.Ps[r * 96 + j] = 0;
    }
  }
  __syncthreads();

  // O = P @ V : 5x4 tiles, K padded to 96
  for (int idx = wave; idx < 20; idx += 4) {
    int ti = idx >> 2, tj = idx & 3;
    floatx4 oa = {};
    #pragma unroll
    for (int k0 = 0; k0 < 96; k0 += 32) {
      short8 ap = *(const short8*)(u.Ps + (ti * 16 + m) * 96 + k0 + quad * 8);
      short8 bv = *(const short8*)(Vt + (tj * 16 + m) * 96 + k0 + quad * 8);
      oa = __builtin_amdgcn_mfma_f32_16x16x32_bf16(ap, bv, oa, 0, 0, 0);
    }
    #pragma unroll
    for (int r = 0; r < 4; r++) {
      int l = ti * 16 + quad * 4 + r;
      if (l < 77)
        o[((size_t)b * 77 + l) * 768 + hh * 64 + tj * 16 + m] = f2bf(oa[r]);
    }
  }
}

// ---------------- final: per-row normalize, mean over n, renormalize ------
__global__ void reduce_kernel(const float* feats, float* out) {
  __shared__ float red[4];
  int mfig = blockIdx.x;   // 0..7
  int t = threadIdx.x;     // 256
  float a0 = 0.f, a1 = 0.f, a2 = 0.f;
  for (int n = 0; n < 64; n++) {
    const float* fr = feats + ((size_t)mfig * 64 + n) * 768;
    float v0 = fr[t], v1 = fr[t + 256], v2 = fr[t + 512];
    float q = blockReduceSum256(v0 * v0 + v1 * v1 + v2 * v2, red);
    float rn = rsqrtf(q);
    a0 += v0 * rn; a1 += v1 * rn; a2 += v2 * rn;
  }
  float q = blockReduceSum256(a0 * a0 + a1 * a1 + a2 * a2, red);
  float rn = rsqrtf(q);
  out[mfig * 768 + t]       = a0 * rn;
  out[mfig * 768 + t + 256] = a1 * rn;
  out[mfig * 768 + t + 512] = a2 * rn;
}

// ---------------------------------------------------------------------------
extern "C" void kernel_launch(void* const* d_in, const int* in_sizes, int n_in,
                              void* d_out, int out_size, void* d_ws,
                              size_t ws_size, hipStream_t stream) {
  (void)in_sizes; (void)n_in; (void)out_size; (void)ws_size;
  const int*   text      = (const int*)d_in[0];
  const float* visf      = (const float*)d_in[1];
  const float* tok_emb   = (const float*)d_in[2];
  const float* pos_emb   = (const float*)d_in[3];
  const float* ln1_w     = (const float*)d_in[4];
  const float* ln1_b     = (const float*)d_in[5];
  const float* in_w      = (const float*)d_in[6];
  const float* in_b      = (const float*)d_in[7];
  const float* out_w     = (const float*)d_in[8];
  const float* out_b     = (const float*)d_in[9];
  const float* ln2_w     = (const float*)d_in[10];
  const float* ln2_b     = (const float*)d_in[11];
  const float* fc_w      = (const float*)d_in[12];
  const float* fc_b      = (const float*)d_in[13];
  const float* pj_w      = (const float*)d_in[14];
  const float* pj_b      = (const float*)d_in[15];
  const float* lnf_w     = (const float*)d_in[16];
  const float* lnf_b     = (const float*)d_in[17];
  const float* text_proj = (const float*)d_in[18];
  float* out = (float*)d_out;

  char* p = (char*)d_ws;
  auto alloc = [&](size_t bytes) {
    char* q = p; p += (bytes + 255) & ~(size_t)255; return q;
  };
  int* posy = (int*)alloc(64 * 4);
  int* eot  = (int*)alloc(64 * 4);
  float* h            = (float*)alloc((size_t)ROWS * 768 * 4);          // 121 MB
  unsigned short* y   = (unsigned short*)alloc((size_t)ROWS * 768 * 2); // 61 MB
  unsigned short* qkv = (unsigned short*)alloc((size_t)ROWS * 2304 * 2);// 182 MB
  unsigned short* ob  = (unsigned short*)alloc((size_t)ROWS * 768 * 2); // 61 MB
  unsigned short* act = qkv;  // aliases qkv+ob (dead when act is live): 242 MB
  float* wt    = (float*)alloc((size_t)768 * 768 * 4);
  unsigned short* afin = (unsigned short*)alloc((size_t)512 * 768 * 2);
  float* feats = (float*)alloc((size_t)512 * 768 * 4);

  idx_kernel<<<1, 64, 0, stream>>>(text, posy, eot);
  transT_kernel<<<(768 * 768) / 256, 256, 0, stream>>>(text_proj, wt);
  embed_kernel<<<ROWS, 192, 0, stream>>>(text, visf, tok_emb, pos_emb, posy, h);

  for (int l = 0; l < 12; l++) {
    ln_kernel<<<ROWS, 256, 0, stream>>>(h, ln1_w + l * 768, ln1_b + l * 768, y);
    gemm_kernel<0><<<dim3(308, 18), 256, 0, stream>>>(
        y, in_w + (size_t)l * 2304 * 768, in_b + l * 2304, qkv, nullptr, 768, 2304);
    attn_kernel<<<dim3(512, 12), 256, 0, stream>>>(qkv, ob);
    gemm_kernel<2><<<dim3(308, 6), 256, 0, stream>>>(
        ob, out_w + (size_t)l * 768 * 768, out_b + l * 768, h, h, 768, 768);
    ln_kernel<<<ROWS, 256, 0, stream>>>(h, ln2_w + l * 768, ln2_b + l * 768, y);
    gemm_kernel<1><<<dim3(308, 24), 256, 0, stream>>>(
        y, fc_w + (size_t)l * 3072 * 768, fc_b + l * 3072, act, nullptr, 768, 3072);
    gemm_kernel<2><<<dim3(308, 6), 256, 0, stream>>>(
        act, pj_w + (size_t)l * 768 * 3072, pj_b + l * 768, h, h, 3072, 768);
  }

  gather_ln_kernel<<<512, 256, 0, stream>>>(h, eot, lnf_w, lnf_b, afin);
  gemm_kernel<3><<<dim3(4, 6), 256, 0, stream>>>(
      afin, wt, nullptr, feats, nullptr, 768, 768);
  reduce_kernel<<<8, 256, 0, stream>>>(feats, out);
}

// Round 2
// 15445.097 us; speedup vs baseline: 1.1255x; 1.1255x over previous
//
#include <hip/hip_runtime.h>

// ---------------------------------------------------------------------------
// CLIP text transformer forward, MI355X/gfx950.
// Shapes: N=64, L=77, D=768, V=8, M=8, H=12 heads (hd=64), 12 layers.
// Rows = M*N*L = 39424 = 308*128 (exact 128-row tiles).
// Round 2: per-layer fp32->bf16 weight pre-conversion (W bytes halved, no
// VALU convert in K-loop), GEMM staged via global_load_lds width=16 (m97
// structure), grid swapped to col-fastest so consecutive blocks share the
// A row-tile and reuse the whole bf16 W strip from L2/LLC.
// ---------------------------------------------------------------------------

typedef short short8 __attribute__((ext_vector_type(8)));
typedef float floatx4 __attribute__((ext_vector_type(4)));
typedef unsigned int uint4v __attribute__((ext_vector_type(4)));
typedef unsigned short ushort4v __attribute__((ext_vector_type(4)));

#define SOV_TOK 49408
#define EOT_TOK 49407
#define ROWS 39424      // 512*77

__device__ __forceinline__ unsigned short f2bf(float f) {
  union { float f; unsigned int u; } v; v.f = f;
  return (unsigned short)((v.u + 0x7fffu + ((v.u >> 16) & 1u)) >> 16);
}

typedef const __attribute__((address_space(1))) void* gptr_t;
typedef __attribute__((address_space(3))) void* lptr_t;
__device__ __forceinline__ void glds16(const void* g, void* l) {
  __builtin_amdgcn_global_load_lds((gptr_t)g, (lptr_t)l, 16, 0, 0);
}

__device__ __forceinline__ float blockReduceSum256(float v, float* red) {
  __syncthreads();                    // protect red reuse across calls
  #pragma unroll
  for (int off = 32; off; off >>= 1) v += __shfl_down(v, off, 64);
  int wave = threadIdx.x >> 6, lane = threadIdx.x & 63;
  if (lane == 0) red[wave] = v;
  __syncthreads();
  return red[0] + red[1] + red[2] + red[3];
}

// ---------------- index scan: first SOV / first EOT per sequence ----------
__global__ void idx_kernel(const int* text, int* posy, int* eot) {
  int n = threadIdx.x;  // 64 threads
  int py = 0, et = 0; bool fp = false, fe = false;
  for (int j = 0; j < 77; j++) {
    int v = text[n * 77 + j];
    if (!fp && v == SOV_TOK) { py = j; fp = true; }
    if (!fe && v == EOT_TOK) { et = j; fe = true; }
  }
  posy[n] = py; eot[n] = et;
}

// ---------------- fp32 -> bf16 weight conversion --------------------------
__global__ void cvt_kernel(const float* src, unsigned short* dst, int n) {
  int i = (blockIdx.x * 256 + threadIdx.x) * 4;
  if (i < n) {
    float4 v = *(const float4*)(src + i);
    ushort4v o;
    o.x = f2bf(v.x); o.y = f2bf(v.y); o.z = f2bf(v.z); o.w = f2bf(v.w);
    *(ushort4v*)(dst + i) = o;
  }
}

// transpose text_proj (D,E) -> bf16 (E,D)
__global__ void transT_kernel(const float* tp, unsigned short* wt) {
  int id = blockIdx.x * 256 + threadIdx.x;   // 768*768 total
  int d = id / 768, e = id % 768;
  wt[(size_t)e * 768 + d] = f2bf(tp[id]);
}

// ---------------- build h = splice(tok_emb, visual) + pos_emb -------------
__global__ void embed_kernel(const int* text, const float* vis,
                             const float* tok_emb, const float* pos_emb,
                             const int* posy, float* h) {
  int bp = blockIdx.x;              // 0..39423 = b*77+p
  int b = bp / 77, p = bp % 77;
  int mm = b >> 6, n = b & 63;
  int py = posy[n];
  int t = threadIdx.x;              // 192 threads * float4 = 768
  const float* srcp;
  if (p >= py && p < py + 8) {
    srcp = vis + ((size_t)mm * 8 + (p - py)) * 768;
  } else {
    int src = (p < py) ? p : p - 7;
    src = src < 0 ? 0 : (src > 76 ? 76 : src);
    int tok = text[n * 77 + src];
    srcp = tok_emb + (size_t)tok * 768;
  }
  float4 v = *(const float4*)(srcp + t * 4);
  float4 pe = *(const float4*)(pos_emb + (size_t)p * 768 + t * 4);
  v.x += pe.x; v.y += pe.y; v.z += pe.z; v.w += pe.w;
  *(float4*)(h + (size_t)bp * 768 + t * 4) = v;
}

// ---------------- row LayerNorm fp32 -> bf16 ------------------------------
__device__ __forceinline__ void ln_row(const float* xr, const float* w,
                                       const float* b, unsigned short* yr,
                                       float* red) {
  int t = threadIdx.x;  // 256
  float v0 = xr[t], v1 = xr[t + 256], v2 = xr[t + 512];
  float s = blockReduceSum256(v0 + v1 + v2, red);
  float mu = s * (1.f / 768.f);
  float d0 = v0 - mu, d1 = v1 - mu, d2 = v2 - mu;
  float q = blockReduceSum256(d0 * d0 + d1 * d1 + d2 * d2, red);
  float rstd = rsqrtf(q * (1.f / 768.f) + 1e-5f);
  yr[t]       = f2bf(d0 * rstd * w[t]       + b[t]);
  yr[t + 256] = f2bf(d1 * rstd * w[t + 256] + b[t + 256]);
  yr[t + 512] = f2bf(d2 * rstd * w[t + 512] + b[t + 512]);
}

__global__ void ln_kernel(const float* x, const float* w, const float* b,
                          unsigned short* y) {
  __shared__ float red[4];
  size_t r = blockIdx.x;
  ln_row(x + r * 768, w, b, y + r * 768, red);
}

// gather the (eot+V-1) token per (m,n) and apply final LN
__global__ void gather_ln_kernel(const float* h, const int* eot,
                                 const float* w, const float* b,
                                 unsigned short* y) {
  __shared__ float red[4];
  int r = blockIdx.x;               // 0..511 = m*64+n
  int n = r & 63;
  size_t row = (size_t)r * 77 + (eot[n] + 7);
  ln_row(h + row * 768, w, b, y + (size_t)r * 768, red);
}

// ---------------- GEMM: C[rows,cols] = A_bf16[rows,K] @ W_bf16[cols,K]^T --
// MODE 0: +bias -> bf16    MODE 1: gelu(+bias) -> bf16
// MODE 2: h += (+bias), fp32 in/out    MODE 3: (+bias?) -> fp32
// grid = (cols/128, rows/128): col-fastest so consecutive blocks share the
// A row-tile and stream the (small, cached) W.
template <int MODE>
__global__ __launch_bounds__(256, 2)
void gemm_kernel(const unsigned short* A, const unsigned short* W,
                 const float* bias, void* outp, const float* resid,
                 int K, int cols) {
  __shared__ __align__(16) unsigned short As[128 * 32];
  __shared__ __align__(16) unsigned short Ws[128 * 32];
  int col0 = blockIdx.x * 128;
  int row0 = blockIdx.y * 128;
  int t = threadIdx.x;
  int wave = t >> 6, lane = t & 63;
  int wr = (wave & 1) * 64;   // wave's 64-row strip
  int wc = (wave >> 1) * 64;  // wave's 64-col strip
  int m = lane & 15, quad = lane >> 4;

  // staging: thread t loads 16B; row = t>>2, k-chunk = (t&3)*8 elems.
  // global_load_lds lands lane data at (wave-uniform base) + lane*16B,
  // which equals row-major As[row*32 + kchunk] exactly.
  int srow = t >> 2, sk = (t & 3) * 8;
  const unsigned short* Ap = A + (size_t)(row0 + srow) * K + sk;
  const unsigned short* Wp = W + (size_t)(col0 + srow) * K + sk;
  size_t half = (size_t)64 * K;
  unsigned short* AsD = As + wave * 512;   // wave*1024 bytes
  unsigned short* WsD = Ws + wave * 512;

  floatx4 acc[4][4] = {};

  for (int kb = 0; kb < K; kb += 32) {
    __syncthreads();   // prev iter's ds_read frag loads complete
    glds16(Ap + kb, AsD);
    glds16(Ap + half + kb, AsD + 2048);
    glds16(Wp + kb, WsD);
    glds16(Wp + half + kb, WsD + 2048);
    __syncthreads();   // vmcnt(0) drain: staged data visible
    short8 af[4], bfm[4];
    #pragma unroll
    for (int i = 0; i < 4; i++)
      af[i] = *(const short8*)(As + (wr + i * 16 + m) * 32 + quad * 8);
    #pragma unroll
    for (int j = 0; j < 4; j++)
      bfm[j] = *(const short8*)(Ws + (wc + j * 16 + m) * 32 + quad * 8);
    #pragma unroll
    for (int i = 0; i < 4; i++)
      #pragma unroll
      for (int j = 0; j < 4; j++)
        acc[i][j] = __builtin_amdgcn_mfma_f32_16x16x32_bf16(af[i], bfm[j],
                                                            acc[i][j], 0, 0, 0);
  }

  // epilogue: C/D layout col = lane&15, row = quad*4+reg
  #pragma unroll
  for (int i = 0; i < 4; i++) {
    #pragma unroll
    for (int j = 0; j < 4; j++) {
      int c = col0 + wc + j * 16 + m;
      float bi = bias ? bias[c] : 0.f;
      int rbase = row0 + wr + i * 16 + quad * 4;
      #pragma unroll
      for (int reg = 0; reg < 4; reg++) {
        size_t idx = (size_t)(rbase + reg) * cols + c;
        float v = acc[i][j][reg] + bi;
        if (MODE == 0) {
          ((unsigned short*)outp)[idx] = f2bf(v);
        } else if (MODE == 1) {
          float g = v / (1.f + __expf(-1.702f * v));
          ((unsigned short*)outp)[idx] = f2bf(g);
        } else if (MODE == 2) {
          float* op = (float*)outp;
          op[idx] = resid[idx] + v;
        } else {
          ((float*)outp)[idx] = v;
        }
      }
    }
  }
}

// ---------------- fused attention per (batch, head) -----------------------
// QK^T via MFMA (lower-triangular tiles only), fp32 softmax, P@V via MFMA.
__global__ __launch_bounds__(256)
void attn_kernel(const unsigned short* qkv, unsigned short* o) {
  __shared__ __align__(16) union U {
    struct { unsigned short Qs[80 * 64]; unsigned short Ks[80 * 64]; } qk;
    unsigned short Ps[80 * 96];
  } u;
  __shared__ __align__(16) unsigned short Vt[64 * 96];
  __shared__ float S[80 * 81];     // stride 81: bank-conflict-free rows

  int b = blockIdx.x, hh = blockIdx.y;
  int t = threadIdx.x, wave = t >> 6, lane = t & 63;
  int m = lane & 15, quad = lane >> 4;
  const unsigned short* base = qkv + (size_t)b * 77 * 2304 + hh * 64;

  // stage Q,K rows (pad rows 77..79 with zeros)
  for (int c = t; c < 640; c += 256) {
    int l = c >> 3, kc = (c & 7) * 8;
    uint4v q = {0, 0, 0, 0}, k = {0, 0, 0, 0};
    if (l < 77) {
      q = *(const uint4v*)(base + (size_t)l * 2304 + kc);
      k = *(const uint4v*)(base + (size_t)l * 2304 + 768 + kc);
    }
    *(uint4v*)(u.qk.Qs + l * 64 + kc) = q;
    *(uint4v*)(u.qk.Ks + l * 64 + kc) = k;
  }
  // stage V transposed: Vt[d][l], l padded to 96
  for (int c = t; c < 768; c += 256) {
    int l = c >> 3, d0 = (c & 7) * 8;
    union { uint4v v; unsigned short s[8]; } vv;
    vv.v = (uint4v){0, 0, 0, 0};
    if (l < 77) vv.v = *(const uint4v*)(base + (size_t)l * 2304 + 1536 + d0);
    #pragma unroll
    for (int j = 0; j < 8; j++) Vt[(d0 + j) * 96 + l] = vv.s[j];
  }
  __syncthreads();

  // S = Q K^T : lower-triangular 16x16 tiles (15 of 25)
  for (int idx = wave; idx < 15; idx += 4) {
    int ti = 0, a2 = 0;
    while (a2 + ti + 1 <= idx) { a2 += ti + 1; ti++; }
    int tj = idx - a2;
    floatx4 sa = {};
    #pragma unroll
    for (int k0 = 0; k0 < 64; k0 += 32) {
      short8 aq = *(const short8*)(u.qk.Qs + (ti * 16 + m) * 64 + k0 + quad * 8);
      short8 bk = *(const short8*)(u.qk.Ks + (tj * 16 + m) * 64 + k0 + quad * 8);
      sa = __builtin_amdgcn_mfma_f32_16x16x32_bf16(aq, bk, sa, 0, 0, 0);
    }
    #pragma unroll
    for (int r = 0; r < 4; r++)
      S[(ti * 16 + quad * 4 + r) * 81 + tj * 16 + m] = sa[r];
  }
  __syncthreads();

  // causal softmax row-per-thread (scale 1/8), write P bf16 (96-padded)
  if (t < 80) {
    int r = t;
    if (r < 77) {
      float mx = -1e30f;
      for (int j = 0; j <= r; j++) mx = fmaxf(mx, S[r * 81 + j]);
      float sum = 0.f;
      for (int j = 0; j <= r; j++) {
        float e = __expf((S[r * 81 + j] - mx) * 0.125f);
        S[r * 81 + j] = e; sum += e;
      }
      float inv = 1.f / sum;
      for (int j = 0; j < 96; j++)
        u.Ps[r * 96 + j] = (j <= r) ? f2bf(S[r * 81 + j] * inv) : (unsigned short)0;
    } else {
      for (int j = 0; j < 96; j++) u.Ps[r * 96 + j] = 0;
    }
  }
  __syncthreads();

  // O = P @ V : 5x4 tiles, K padded to 96
  for (int idx = wave; idx < 20; idx += 4) {
    int ti = idx >> 2, tj = idx & 3;
    floatx4 oa = {};
    #pragma unroll
    for (int k0 = 0; k0 < 96; k0 += 32) {
      short8 ap = *(const short8*)(u.Ps + (ti * 16 + m) * 96 + k0 + quad * 8);
      short8 bv = *(const short8*)(Vt + (tj * 16 + m) * 96 + k0 + quad * 8);
      oa = __builtin_amdgcn_mfma_f32_16x16x32_bf16(ap, bv, oa, 0, 0, 0);
    }
    #pragma unroll
    for (int r = 0; r < 4; r++) {
      int l = ti * 16 + quad * 4 + r;
      if (l < 77)
        o[((size_t)b * 77 + l) * 768 + hh * 64 + tj * 16 + m] = f2bf(oa[r]);
    }
  }
}

// ---------------- final: per-row normalize, mean over n, renormalize ------
__global__ void reduce_kernel(const float* feats, float* out) {
  __shared__ float red[4];
  int mfig = blockIdx.x;   // 0..7
  int t = threadIdx.x;     // 256
  float a0 = 0.f, a1 = 0.f, a2 = 0.f;
  for (int n = 0; n < 64; n++) {
    const float* fr = feats + ((size_t)mfig * 64 + n) * 768;
    float v0 = fr[t], v1 = fr[t + 256], v2 = fr[t + 512];
    float q = blockReduceSum256(v0 * v0 + v1 * v1 + v2 * v2, red);
    float rn = rsqrtf(q);
    a0 += v0 * rn; a1 += v1 * rn; a2 += v2 * rn;
  }
  float q = blockReduceSum256(a0 * a0 + a1 * a1 + a2 * a2, red);
  float rn = rsqrtf(q);
  out[mfig * 768 + t]       = a0 * rn;
  out[mfig * 768 + t + 256] = a1 * rn;
  out[mfig * 768 + t + 512] = a2 * rn;
}

// ---------------------------------------------------------------------------
extern "C" void kernel_launch(void* const* d_in, const int* in_sizes, int n_in,
                              void* d_out, int out_size, void* d_ws,
                              size_t ws_size, hipStream_t stream) {
  (void)in_sizes; (void)n_in; (void)out_size; (void)ws_size;
  const int*   text      = (const int*)d_in[0];
  const float* visf      = (const float*)d_in[1];
  const float* tok_emb   = (const float*)d_in[2];
  const float* pos_emb   = (const float*)d_in[3];
  const float* ln1_w     = (const float*)d_in[4];
  const float* ln1_b     = (const float*)d_in[5];
  const float* in_w      = (const float*)d_in[6];
  const float* in_b      = (const float*)d_in[7];
  const float* out_w     = (const float*)d_in[8];
  const float* out_b     = (const float*)d_in[9];
  const float* ln2_w     = (const float*)d_in[10];
  const float* ln2_b     = (const float*)d_in[11];
  const float* fc_w      = (const float*)d_in[12];
  const float* fc_b      = (const float*)d_in[13];
  const float* pj_w      = (const float*)d_in[14];
  const float* pj_b      = (const float*)d_in[15];
  const float* lnf_w     = (const float*)d_in[16];
  const float* lnf_b     = (const float*)d_in[17];
  const float* text_proj = (const float*)d_in[18];
  float* out = (float*)d_out;

  char* p = (char*)d_ws;
  auto alloc = [&](size_t bytes) {
    char* q = p; p += (bytes + 255) & ~(size_t)255; return q;
  };
  int* posy = (int*)alloc(64 * 4);
  int* eot  = (int*)alloc(64 * 4);
  float* h            = (float*)alloc((size_t)ROWS * 768 * 4);          // 121 MB
  unsigned short* y   = (unsigned short*)alloc((size_t)ROWS * 768 * 2); // 61 MB
  unsigned short* qkv = (unsigned short*)alloc((size_t)ROWS * 2304 * 2);// 182 MB
  unsigned short* ob  = (unsigned short*)alloc((size_t)ROWS * 768 * 2); // 61 MB
  unsigned short* act = qkv;  // aliases qkv+ob (dead when act is live)
  // per-layer bf16 weight buffer (reused each layer; stream-ordered)
  unsigned short* wqkv = (unsigned short*)alloc((size_t)2304 * 768 * 2);
  unsigned short* wout = (unsigned short*)alloc((size_t)768 * 768 * 2);
  unsigned short* wfc  = (unsigned short*)alloc((size_t)3072 * 768 * 2);
  unsigned short* wpj  = (unsigned short*)alloc((size_t)768 * 3072 * 2);
  unsigned short* wt   = (unsigned short*)alloc((size_t)768 * 768 * 2);
  unsigned short* afin = (unsigned short*)alloc((size_t)512 * 768 * 2);
  float* feats = (float*)alloc((size_t)512 * 768 * 4);

  idx_kernel<<<1, 64, 0, stream>>>(text, posy, eot);
  transT_kernel<<<(768 * 768) / 256, 256, 0, stream>>>(text_proj, wt);
  embed_kernel<<<ROWS, 192, 0, stream>>>(text, visf, tok_emb, pos_emb, posy, h);

  const int NQKV = 2304 * 768, NOUT = 768 * 768, NFC = 3072 * 768;
  for (int l = 0; l < 12; l++) {
    cvt_kernel<<<NQKV / 1024, 256, 0, stream>>>(in_w + (size_t)l * NQKV, wqkv, NQKV);
    cvt_kernel<<<NOUT / 1024, 256, 0, stream>>>(out_w + (size_t)l * NOUT, wout, NOUT);
    cvt_kernel<<<NFC / 1024, 256, 0, stream>>>(fc_w + (size_t)l * NFC, wfc, NFC);
    cvt_kernel<<<NFC / 1024, 256, 0, stream>>>(pj_w + (size_t)l * NFC, wpj, NFC);

    ln_kernel<<<ROWS, 256, 0, stream>>>(h, ln1_w + l * 768, ln1_b + l * 768, y);
    gemm_kernel<0><<<dim3(18, 308), 256, 0, stream>>>(
        y, wqkv, in_b + l * 2304, qkv, nullptr, 768, 2304);
    attn_kernel<<<dim3(512, 12), 256, 0, stream>>>(qkv, ob);
    gemm_kernel<2><<<dim3(6, 308), 256, 0, stream>>>(
        ob, wout, out_b + l * 768, h, h, 768, 768);
    ln_kernel<<<ROWS, 256, 0, stream>>>(h, ln2_w + l * 768, ln2_b + l * 768, y);
    gemm_kernel<1><<<dim3(24, 308), 256, 0, stream>>>(
        y, wfc, fc_b + l * 3072, act, nullptr, 768, 3072);
    gemm_kernel<2><<<dim3(6, 308), 256, 0, stream>>>(
        act, wpj, pj_b + l * 768, h, h, 3072, 768);
  }

  gather_ln_kernel<<<512, 256, 0, stream>>>(h, eot, lnf_w, lnf_b, afin);
  gemm_kernel<3><<<dim3(6, 4), 256, 0, stream>>>(
      afin, wt, nullptr, feats, nullptr, 768, 768);
  reduce_kernel<<<8, 256, 0, stream>>>(feats, out);
}

// Round 3
// 14794.453 us; speedup vs baseline: 1.1750x; 1.0440x over previous
//
#include <hip/hip_runtime.h>

// ---------------------------------------------------------------------------
// CLIP text transformer forward, MI355X/gfx950.
// Shapes: N=64, L=77, D=768, V=8, M=8, H=12 heads (hd=64), 12 layers.
// Rows = M*N*L = 39424 = 308*128 (exact 128-row tiles).
// Round 3: XCD-aware block swizzle in the GEMM — physical blocks round-robin
// across 8 XCDs (per-XCD private L2), so logical id L=(P%8)*(G/8)+P/8 gives
// each XCD a contiguous run of row-groups: the shared A row-tile is fetched
// from HBM once per chip instead of once per XCD (was the 8x A over-fetch,
// FETCH_SIZE 857 MB on the big GEMMs).
// ---------------------------------------------------------------------------

typedef short short8 __attribute__((ext_vector_type(8)));
typedef float floatx4 __attribute__((ext_vector_type(4)));
typedef unsigned int uint4v __attribute__((ext_vector_type(4)));
typedef unsigned short ushort4v __attribute__((ext_vector_type(4)));

#define SOV_TOK 49408
#define EOT_TOK 49407
#define ROWS 39424      // 512*77

__device__ __forceinline__ unsigned short f2bf(float f) {
  union { float f; unsigned int u; } v; v.f = f;
  return (unsigned short)((v.u + 0x7fffu + ((v.u >> 16) & 1u)) >> 16);
}

typedef const __attribute__((address_space(1))) void* gptr_t;
typedef __attribute__((address_space(3))) void* lptr_t;
__device__ __forceinline__ void glds16(const void* g, void* l) {
  __builtin_amdgcn_global_load_lds((gptr_t)g, (lptr_t)l, 16, 0, 0);
}

__device__ __forceinline__ float blockReduceSum256(float v, float* red) {
  __syncthreads();                    // protect red reuse across calls
  #pragma unroll
  for (int off = 32; off; off >>= 1) v += __shfl_down(v, off, 64);
  int wave = threadIdx.x >> 6, lane = threadIdx.x & 63;
  if (lane == 0) red[wave] = v;
  __syncthreads();
  return red[0] + red[1] + red[2] + red[3];
}

// ---------------- index scan: first SOV / first EOT per sequence ----------
__global__ void idx_kernel(const int* text, int* posy, int* eot) {
  int n = threadIdx.x;  // 64 threads
  int py = 0, et = 0; bool fp = false, fe = false;
  for (int j = 0; j < 77; j++) {
    int v = text[n * 77 + j];
    if (!fp && v == SOV_TOK) { py = j; fp = true; }
    if (!fe && v == EOT_TOK) { et = j; fe = true; }
  }
  posy[n] = py; eot[n] = et;
}

// ---------------- fp32 -> bf16 weight conversion --------------------------
__global__ void cvt_kernel(const float* src, unsigned short* dst, int n) {
  int i = (blockIdx.x * 256 + threadIdx.x) * 4;
  if (i < n) {
    float4 v = *(const float4*)(src + i);
    ushort4v o;
    o.x = f2bf(v.x); o.y = f2bf(v.y); o.z = f2bf(v.z); o.w = f2bf(v.w);
    *(ushort4v*)(dst + i) = o;
  }
}

// transpose text_proj (D,E) -> bf16 (E,D)
__global__ void transT_kernel(const float* tp, unsigned short* wt) {
  int id = blockIdx.x * 256 + threadIdx.x;   // 768*768 total
  int d = id / 768, e = id % 768;
  wt[(size_t)e * 768 + d] = f2bf(tp[id]);
}

// ---------------- build h = splice(tok_emb, visual) + pos_emb -------------
__global__ void embed_kernel(const int* text, const float* vis,
                             const float* tok_emb, const float* pos_emb,
                             const int* posy, float* h) {
  int bp = blockIdx.x;              // 0..39423 = b*77+p
  int b = bp / 77, p = bp % 77;
  int mm = b >> 6, n = b & 63;
  int py = posy[n];
  int t = threadIdx.x;              // 192 threads * float4 = 768
  const float* srcp;
  if (p >= py && p < py + 8) {
    srcp = vis + ((size_t)mm * 8 + (p - py)) * 768;
  } else {
    int src = (p < py) ? p : p - 7;
    src = src < 0 ? 0 : (src > 76 ? 76 : src);
    int tok = text[n * 77 + src];
    srcp = tok_emb + (size_t)tok * 768;
  }
  float4 v = *(const float4*)(srcp + t * 4);
  float4 pe = *(const float4*)(pos_emb + (size_t)p * 768 + t * 4);
  v.x += pe.x; v.y += pe.y; v.z += pe.z; v.w += pe.w;
  *(float4*)(h + (size_t)bp * 768 + t * 4) = v;
}

// ---------------- row LayerNorm fp32 -> bf16 ------------------------------
__device__ __forceinline__ void ln_row(const float* xr, const float* w,
                                       const float* b, unsigned short* yr,
                                       float* red) {
  int t = threadIdx.x;  // 256
  float v0 = xr[t], v1 = xr[t + 256], v2 = xr[t + 512];
  float s = blockReduceSum256(v0 + v1 + v2, red);
  float mu = s * (1.f / 768.f);
  float d0 = v0 - mu, d1 = v1 - mu, d2 = v2 - mu;
  float q = blockReduceSum256(d0 * d0 + d1 * d1 + d2 * d2, red);
  float rstd = rsqrtf(q * (1.f / 768.f) + 1e-5f);
  yr[t]       = f2bf(d0 * rstd * w[t]       + b[t]);
  yr[t + 256] = f2bf(d1 * rstd * w[t + 256] + b[t + 256]);
  yr[t + 512] = f2bf(d2 * rstd * w[t + 512] + b[t + 512]);
}

__global__ void ln_kernel(const float* x, const float* w, const float* b,
                          unsigned short* y) {
  __shared__ float red[4];
  size_t r = blockIdx.x;
  ln_row(x + r * 768, w, b, y + r * 768, red);
}

// gather the (eot+V-1) token per (m,n) and apply final LN
__global__ void gather_ln_kernel(const float* h, const int* eot,
                                 const float* w, const float* b,
                                 unsigned short* y) {
  __shared__ float red[4];
  int r = blockIdx.x;               // 0..511 = m*64+n
  int n = r & 63;
  size_t row = (size_t)r * 77 + (eot[n] + 7);
  ln_row(h + row * 768, w, b, y + (size_t)r * 768, red);
}

// ---------------- GEMM: C[rows,cols] = A_bf16[rows,K] @ W_bf16[cols,K]^T --
// MODE 0: +bias -> bf16    MODE 1: gelu(+bias) -> bf16
// MODE 2: h += (+bias), fp32 in/out    MODE 3: (+bias?) -> fp32
// XCD swizzle: physical block P lands on XCD P%8; logical (col-fastest)
// id L=(P%8)*(G/8)+P/8 gives each XCD a contiguous row-group range.
template <int MODE>
__global__ __launch_bounds__(256, 2)
void gemm_kernel(const unsigned short* A, const unsigned short* W,
                 const float* bias, void* outp, const float* resid,
                 int K, int cols) {
  __shared__ __align__(16) unsigned short As[128 * 32];
  __shared__ __align__(16) unsigned short Ws[128 * 32];
  int nbx = gridDim.x;
  int G = nbx * gridDim.y;
  int P = blockIdx.y * nbx + blockIdx.x;
  int Lid = ((G & 7) == 0) ? (P & 7) * (G >> 3) + (P >> 3) : P;
  int col0 = (Lid % nbx) * 128;
  int row0 = (Lid / nbx) * 128;
  int t = threadIdx.x;
  int wave = t >> 6, lane = t & 63;
  int wr = (wave & 1) * 64;   // wave's 64-row strip
  int wc = (wave >> 1) * 64;  // wave's 64-col strip
  int m = lane & 15, quad = lane >> 4;

  // staging: thread t loads 16B; row = t>>2, k-chunk = (t&3)*8 elems.
  // global_load_lds lands lane data at (wave-uniform base) + lane*16B,
  // which equals row-major As[row*32 + kchunk] exactly.
  int srow = t >> 2, sk = (t & 3) * 8;
  const unsigned short* Ap = A + (size_t)(row0 + srow) * K + sk;
  const unsigned short* Wp = W + (size_t)(col0 + srow) * K + sk;
  size_t half = (size_t)64 * K;
  unsigned short* AsD = As + wave * 512;   // wave*1024 bytes
  unsigned short* WsD = Ws + wave * 512;

  floatx4 acc[4][4] = {};

  for (int kb = 0; kb < K; kb += 32) {
    __syncthreads();   // prev iter's ds_read frag loads complete
    glds16(Ap + kb, AsD);
    glds16(Ap + half + kb, AsD + 2048);
    glds16(Wp + kb, WsD);
    glds16(Wp + half + kb, WsD + 2048);
    __syncthreads();   // vmcnt(0) drain: staged data visible
    short8 af[4], bfm[4];
    #pragma unroll
    for (int i = 0; i < 4; i++)
      af[i] = *(const short8*)(As + (wr + i * 16 + m) * 32 + quad * 8);
    #pragma unroll
    for (int j = 0; j < 4; j++)
      bfm[j] = *(const short8*)(Ws + (wc + j * 16 + m) * 32 + quad * 8);
    #pragma unroll
    for (int i = 0; i < 4; i++)
      #pragma unroll
      for (int j = 0; j < 4; j++)
        acc[i][j] = __builtin_amdgcn_mfma_f32_16x16x32_bf16(af[i], bfm[j],
                                                            acc[i][j], 0, 0, 0);
  }

  // epilogue: C/D layout col = lane&15, row = quad*4+reg
  #pragma unroll
  for (int i = 0; i < 4; i++) {
    #pragma unroll
    for (int j = 0; j < 4; j++) {
      int c = col0 + wc + j * 16 + m;
      float bi = bias ? bias[c] : 0.f;
      int rbase = row0 + wr + i * 16 + quad * 4;
      #pragma unroll
      for (int reg = 0; reg < 4; reg++) {
        size_t idx = (size_t)(rbase + reg) * cols + c;
        float v = acc[i][j][reg] + bi;
        if (MODE == 0) {
          ((unsigned short*)outp)[idx] = f2bf(v);
        } else if (MODE == 1) {
          float g = v / (1.f + __expf(-1.702f * v));
          ((unsigned short*)outp)[idx] = f2bf(g);
        } else if (MODE == 2) {
          float* op = (float*)outp;
          op[idx] = resid[idx] + v;
        } else {
          ((float*)outp)[idx] = v;
        }
      }
    }
  }
}

// ---------------- fused attention per (batch, head) -----------------------
// QK^T via MFMA (lower-triangular tiles only), fp32 softmax, P@V via MFMA.
__global__ __launch_bounds__(256)
void attn_kernel(const unsigned short* qkv, unsigned short* o) {
  __shared__ __align__(16) union U {
    struct { unsigned short Qs[80 * 64]; unsigned short Ks[80 * 64]; } qk;
    unsigned short Ps[80 * 96];
  } u;
  __shared__ __align__(16) unsigned short Vt[64 * 96];
  __shared__ float S[80 * 81];     // stride 81: bank-conflict-free rows

  int b = blockIdx.x, hh = blockIdx.y;
  int t = threadIdx.x, wave = t >> 6, lane = t & 63;
  int m = lane & 15, quad = lane >> 4;
  const unsigned short* base = qkv + (size_t)b * 77 * 2304 + hh * 64;

  // stage Q,K rows (pad rows 77..79 with zeros)
  for (int c = t; c < 640; c += 256) {
    int l = c >> 3, kc = (c & 7) * 8;
    uint4v q = {0, 0, 0, 0}, k = {0, 0, 0, 0};
    if (l < 77) {
      q = *(const uint4v*)(base + (size_t)l * 2304 + kc);
      k = *(const uint4v*)(base + (size_t)l * 2304 + 768 + kc);
    }
    *(uint4v*)(u.qk.Qs + l * 64 + kc) = q;
    *(uint4v*)(u.qk.Ks + l * 64 + kc) = k;
  }
  // stage V transposed: Vt[d][l], l padded to 96
  for (int c = t; c < 768; c += 256) {
    int l = c >> 3, d0 = (c & 7) * 8;
    union { uint4v v; unsigned short s[8]; } vv;
    vv.v = (uint4v){0, 0, 0, 0};
    if (l < 77) vv.v = *(const uint4v*)(base + (size_t)l * 2304 + 1536 + d0);
    #pragma unroll
    for (int j = 0; j < 8; j++) Vt[(d0 + j) * 96 + l] = vv.s[j];
  }
  __syncthreads();

  // S = Q K^T : lower-triangular 16x16 tiles (15 of 25)
  for (int idx = wave; idx < 15; idx += 4) {
    int ti = 0, a2 = 0;
    while (a2 + ti + 1 <= idx) { a2 += ti + 1; ti++; }
    int tj = idx - a2;
    floatx4 sa = {};
    #pragma unroll
    for (int k0 = 0; k0 < 64; k0 += 32) {
      short8 aq = *(const short8*)(u.qk.Qs + (ti * 16 + m) * 64 + k0 + quad * 8);
      short8 bk = *(const short8*)(u.qk.Ks + (tj * 16 + m) * 64 + k0 + quad * 8);
      sa = __builtin_amdgcn_mfma_f32_16x16x32_bf16(aq, bk, sa, 0, 0, 0);
    }
    #pragma unroll
    for (int r = 0; r < 4; r++)
      S[(ti * 16 + quad * 4 + r) * 81 + tj * 16 + m] = sa[r];
  }
  __syncthreads();

  // causal softmax row-per-thread (scale 1/8), write P bf16 (96-padded)
  if (t < 80) {
    int r = t;
    if (r < 77) {
      float mx = -1e30f;
      for (int j = 0; j <= r; j++) mx = fmaxf(mx, S[r * 81 + j]);
      float sum = 0.f;
      for (int j = 0; j <= r; j++) {
        float e = __expf((S[r * 81 + j] - mx) * 0.125f);
        S[r * 81 + j] = e; sum += e;
      }
      float inv = 1.f / sum;
      for (int j = 0; j < 96; j++)
        u.Ps[r * 96 + j] = (j <= r) ? f2bf(S[r * 81 + j] * inv) : (unsigned short)0;
    } else {
      for (int j = 0; j < 96; j++) u.Ps[r * 96 + j] = 0;
    }
  }
  __syncthreads();

  // O = P @ V : 5x4 tiles, K padded to 96
  for (int idx = wave; idx < 20; idx += 4) {
    int ti = idx >> 2, tj = idx & 3;
    floatx4 oa = {};
    #pragma unroll
    for (int k0 = 0; k0 < 96; k0 += 32) {
      short8 ap = *(const short8*)(u.Ps + (ti * 16 + m) * 96 + k0 + quad * 8);
      short8 bv = *(const short8*)(Vt + (tj * 16 + m) * 96 + k0 + quad * 8);
      oa = __builtin_amdgcn_mfma_f32_16x16x32_bf16(ap, bv, oa, 0, 0, 0);
    }
    #pragma unroll
    for (int r = 0; r < 4; r++) {
      int l = ti * 16 + quad * 4 + r;
      if (l < 77)
        o[((size_t)b * 77 + l) * 768 + hh * 64 + tj * 16 + m] = f2bf(oa[r]);
    }
  }
}

// ---------------- final: per-row normalize, mean over n, renormalize ------
__global__ void reduce_kernel(const float* feats, float* out) {
  __shared__ float red[4];
  int mfig = blockIdx.x;   // 0..7
  int t = threadIdx.x;     // 256
  float a0 = 0.f, a1 = 0.f, a2 = 0.f;
  for (int n = 0; n < 64; n++) {
    const float* fr = feats + ((size_t)mfig * 64 + n) * 768;
    float v0 = fr[t], v1 = fr[t + 256], v2 = fr[t + 512];
    float q = blockReduceSum256(v0 * v0 + v1 * v1 + v2 * v2, red);
    float rn = rsqrtf(q);
    a0 += v0 * rn; a1 += v1 * rn; a2 += v2 * rn;
  }
  float q = blockReduceSum256(a0 * a0 + a1 * a1 + a2 * a2, red);
  float rn = rsqrtf(q);
  out[mfig * 768 + t]       = a0 * rn;
  out[mfig * 768 + t + 256] = a1 * rn;
  out[mfig * 768 + t + 512] = a2 * rn;
}

// ---------------------------------------------------------------------------
extern "C" void kernel_launch(void* const* d_in, const int* in_sizes, int n_in,
                              void* d_out, int out_size, void* d_ws,
                              size_t ws_size, hipStream_t stream) {
  (void)in_sizes; (void)n_in; (void)out_size; (void)ws_size;
  const int*   text      = (const int*)d_in[0];
  const float* visf      = (const float*)d_in[1];
  const float* tok_emb   = (const float*)d_in[2];
  const float* pos_emb   = (const float*)d_in[3];
  const float* ln1_w     = (const float*)d_in[4];
  const float* ln1_b     = (const float*)d_in[5];
  const float* in_w      = (const float*)d_in[6];
  const float* in_b      = (const float*)d_in[7];
  const float* out_w     = (const float*)d_in[8];
  const float* out_b     = (const float*)d_in[9];
  const float* ln2_w     = (const float*)d_in[10];
  const float* ln2_b     = (const float*)d_in[11];
  const float* fc_w      = (const float*)d_in[12];
  const float* fc_b      = (const float*)d_in[13];
  const float* pj_w      = (const float*)d_in[14];
  const float* pj_b      = (const float*)d_in[15];
  const float* lnf_w     = (const float*)d_in[16];
  const float* lnf_b     = (const float*)d_in[17];
  const float* text_proj = (const float*)d_in[18];
  float* out = (float*)d_out;

  char* p = (char*)d_ws;
  auto alloc = [&](size_t bytes) {
    char* q = p; p += (bytes + 255) & ~(size_t)255; return q;
  };
  int* posy = (int*)alloc(64 * 4);
  int* eot  = (int*)alloc(64 * 4);
  float* h            = (float*)alloc((size_t)ROWS * 768 * 4);          // 121 MB
  unsigned short* y   = (unsigned short*)alloc((size_t)ROWS * 768 * 2); // 61 MB
  unsigned short* qkv = (unsigned short*)alloc((size_t)ROWS * 2304 * 2);// 182 MB
  unsigned short* ob  = (unsigned short*)alloc((size_t)ROWS * 768 * 2); // 61 MB
  unsigned short* act = qkv;  // aliases qkv+ob (dead when act is live)
  // per-layer bf16 weight buffer (reused each layer; stream-ordered)
  unsigned short* wqkv = (unsigned short*)alloc((size_t)2304 * 768 * 2);
  unsigned short* wout = (unsigned short*)alloc((size_t)768 * 768 * 2);
  unsigned short* wfc  = (unsigned short*)alloc((size_t)3072 * 768 * 2);
  unsigned short* wpj  = (unsigned short*)alloc((size_t)768 * 3072 * 2);
  unsigned short* wt   = (unsigned short*)alloc((size_t)768 * 768 * 2);
  unsigned short* afin = (unsigned short*)alloc((size_t)512 * 768 * 2);
  float* feats = (float*)alloc((size_t)512 * 768 * 4);

  idx_kernel<<<1, 64, 0, stream>>>(text, posy, eot);
  transT_kernel<<<(768 * 768) / 256, 256, 0, stream>>>(text_proj, wt);
  embed_kernel<<<ROWS, 192, 0, stream>>>(text, visf, tok_emb, pos_emb, posy, h);

  const int NQKV = 2304 * 768, NOUT = 768 * 768, NFC = 3072 * 768;
  for (int l = 0; l < 12; l++) {
    cvt_kernel<<<NQKV / 1024, 256, 0, stream>>>(in_w + (size_t)l * NQKV, wqkv, NQKV);
    cvt_kernel<<<NOUT / 1024, 256, 0, stream>>>(out_w + (size_t)l * NOUT, wout, NOUT);
    cvt_kernel<<<NFC / 1024, 256, 0, stream>>>(fc_w + (size_t)l * NFC, wfc, NFC);
    cvt_kernel<<<NFC / 1024, 256, 0, stream>>>(pj_w + (size_t)l * NFC, wpj, NFC);

    ln_kernel<<<ROWS, 256, 0, stream>>>(h, ln1_w + l * 768, ln1_b + l * 768, y);
    gemm_kernel<0><<<dim3(18, 308), 256, 0, stream>>>(
        y, wqkv, in_b + l * 2304, qkv, nullptr, 768, 2304);
    attn_kernel<<<dim3(512, 12), 256, 0, stream>>>(qkv, ob);
    gemm_kernel<2><<<dim3(6, 308), 256, 0, stream>>>(
        ob, wout, out_b + l * 768, h, h, 768, 768);
    ln_kernel<<<ROWS, 256, 0, stream>>>(h, ln2_w + l * 768, ln2_b + l * 768, y);
    gemm_kernel<1><<<dim3(24, 308), 256, 0, stream>>>(
        y, wfc, fc_b + l * 3072, act, nullptr, 768, 3072);
    gemm_kernel<2><<<dim3(6, 308), 256, 0, stream>>>(
        act, wpj, pj_b + l * 768, h, h, 3072, 768);
  }

  gather_ln_kernel<<<512, 256, 0, stream>>>(h, eot, lnf_w, lnf_b, afin);
  gemm_kernel<3><<<dim3(6, 4), 256, 0, stream>>>(
      afin, wt, nullptr, feats, nullptr, 768, 768);
  reduce_kernel<<<8, 256, 0, stream>>>(feats, out);
}